// Round 2
// baseline (12074.860 us; speedup 1.0000x reference)
//
#include <hip/hip_runtime.h>
#include <hip/hip_bf16.h>

#define DEVI __device__ __forceinline__

namespace {

constexpr int nB = 256, nT = 64, nC = 4880, nD = 128, nH = 1024, nNT = 101, nND = 10;

typedef __attribute__((ext_vector_type(8))) short bfrag;   // 8 bf16 = 4 VGPR (MFMA A/B)
typedef __attribute__((ext_vector_type(4))) float ffrag;   // MFMA C/D
typedef __attribute__((ext_vector_type(4))) unsigned int uvec4;

DEVI ffrag mfma16(bfrag a, bfrag b, ffrag c) {
  return __builtin_amdgcn_mfma_f32_16x16x32_bf16(a, b, c, 0, 0, 0);
}

DEVI unsigned short f2b(float x) {
  __hip_bfloat16 h = __float2bfloat16(x);
  return *reinterpret_cast<unsigned short*>(&h);
}
DEVI float b2f(unsigned short u) {
  __hip_bfloat16 h;
  *reinterpret_cast<unsigned short*>(&h) = u;
  return __bfloat162float(h);
}
DEVI float sigm(float x) { return 1.f / (1.f + expf(-x)); }

// ---------------------------------------------------------------------------
// Double-buffered bf16 MFMA tile stream (used by GRU / VAE kernels).
// ---------------------------------------------------------------------------
template<int NS>
DEVI void mm_stream(ffrag (&acc)[NS],
                    const unsigned short* __restrict__ A, int lda, int K,
                    const unsigned short* const (&Wp)[NS], int ldw,
                    int m0, int n0, int tid, int lane, int mq, int nq,
                    unsigned short* As, unsigned short* Ws) {
  const int r = tid >> 3, blk = tid & 7;
  const int wrOff = (r * 8 + (blk ^ (r & 7))) * 8;   // ushort offset
  const int ra = mq * 16 + (lane & 15);              // A-frag row (m)
  const int rw = nq * 16 + (lane & 15);              // W-frag row (n)
  const int q = lane >> 4;                           // k-quadrant
  const int nc = K >> 6;                             // 64-wide K chunks

  uvec4 va = *(const uvec4*)(A + (size_t)(m0 + r) * lda + blk * 8);
  uvec4 vw[NS];
#pragma unroll
  for (int s = 0; s < NS; ++s)
    vw[s] = *(const uvec4*)(Wp[s] + (size_t)(n0 + r) * ldw + blk * 8);
  *(uvec4*)(As + wrOff) = va;
#pragma unroll
  for (int s = 0; s < NS; ++s) *(uvec4*)(Ws + s * 2048 + wrOff) = vw[s];

  for (int ci = 0; ci < nc; ++ci) {
    __syncthreads();
    const int cur = ci & 1;
    const bool more = (ci + 1) < nc;
    if (more) {
      const int k0 = (ci + 1) << 6;
      va = *(const uvec4*)(A + (size_t)(m0 + r) * lda + k0 + blk * 8);
#pragma unroll
      for (int s = 0; s < NS; ++s)
        vw[s] = *(const uvec4*)(Wp[s] + (size_t)(n0 + r) * ldw + k0 + blk * 8);
    }
    const unsigned short* Ab = As + cur * 2048;
    const unsigned short* Wb = Ws + cur * (NS * 2048);
#pragma unroll
    for (int kk = 0; kk < 2; ++kk) {
      bfrag af = *(const bfrag*)(Ab + (ra * 8 + ((kk * 4 + q) ^ (ra & 7))) * 8);
#pragma unroll
      for (int s = 0; s < NS; ++s) {
        bfrag wf = *(const bfrag*)(Wb + s * 2048 + (rw * 8 + ((kk * 4 + q) ^ (rw & 7))) * 8);
        acc[s] = mfma16(af, wf, acc[s]);
      }
    }
    if (more) {
      const int nx = cur ^ 1;
      *(uvec4*)(As + nx * 2048 + wrOff) = va;
#pragma unroll
      for (int s = 0; s < NS; ++s)
        *(uvec4*)(Ws + nx * (NS * 2048) + s * 2048 + wrOff) = vw[s];
    }
  }
  __syncthreads();
}

// ---- fp32 -> bf16 bulk convert (n divisible by 1024) ----
__global__ void k_cvt(const float* __restrict__ s, unsigned short* __restrict__ d, int n) {
  int i = blockIdx.x * blockDim.x + threadIdx.x;
  float4 v = ((const float4*)s)[i];
  unsigned int u0 = (unsigned int)f2b(v.x) | ((unsigned int)f2b(v.y) << 16);
  unsigned int u1 = (unsigned int)f2b(v.z) | ((unsigned int)f2b(v.w) << 16);
  ((uint2*)d)[i] = make_uint2(u0, u1);
}

// ---- LLM diagnosis mask ----
__global__ void k_mask(const int* __restrict__ llm, float* __restrict__ outm) {
  int c = blockIdx.x * 256 + threadIdx.x;
  int b = blockIdx.y;
  if (c >= nC) return;
  const int* lr = llm + b * nND;
  float v = 0.f;
#pragma unroll
  for (int i = 0; i < nND; ++i) v = (lr[i] == c) ? 1.f : v;
  outm[(size_t)b * nC + c] = v;
}

// ---- sparse visit embedding ----
__global__ void k_embed(const float* __restrict__ Hs, const float* __restrict__ emb,
                        unsigned short* __restrict__ ve) {
  __shared__ float tile[4][16][128];
  const int b = blockIdx.x;
  const int tid = threadIdx.x;
  const int w = tid >> 6, lane = tid & 63;
  float* tw = &tile[w][0][0];
  for (int i = lane; i < 16 * 128; i += 64) tw[i] = 0.f;
  const float* hb = Hs + (size_t)b * nC * nT;
  const int tq = w * 16;
  const int tl = lane & 15;
  const int co = lane >> 4;
  for (int cb = 0; cb < nC; cb += 4) {
    const int c = cb + co;
    float v = hb[(size_t)c * nT + tq + tl];
    unsigned long long m = __ballot(v != 0.f);
    while (m) {
      const int p = __ffsll(m) - 1;
      m &= m - 1;
      const int cc = cb + (p >> 4);
      const int tt = p & 15;
      const float vv = __shfl(v, p);
      const float* er = emb + (size_t)cc * nD;
      tile[w][tt][lane]      += vv * er[lane];
      tile[w][tt][lane + 64] += vv * er[lane + 64];
    }
  }
  for (int rr = 0; rr < 16; ++rr) {
    unsigned short* o = ve + ((size_t)b * nT + tq + rr) * nD;
    o[lane]      = f2b(tile[w][rr][lane]);
    o[lane + 64] = f2b(tile[w][rr][lane + 64]);
  }
}

// ---- one GRU step ----
__global__ __launch_bounds__(256) void k_gru(
    int t,
    const unsigned short* __restrict__ hib, const float* __restrict__ hif,
    const unsigned short* __restrict__ ve,
    const unsigned short* __restrict__ Whh, const unsigned short* __restrict__ Wih,
    const float* __restrict__ bih, const float* __restrict__ bhh,
    float* __restrict__ hof, unsigned short* __restrict__ hob,
    unsigned short* __restrict__ hsb) {
  __shared__ __align__(16) unsigned short As[2 * 2048];
  __shared__ __align__(16) unsigned short Ws[2 * 3 * 2048];
  const int tid = threadIdx.x, lane = tid & 63, w = tid >> 6;
  const int mq = w & 1, nq = w >> 1;
  const int m0 = blockIdx.x * 32, n0 = blockIdx.y * 32;

  ffrag acc1[3] = {};
  const unsigned short* const Wp1[3] = {Whh, Whh + (size_t)nH * nH, Whh + (size_t)2 * nH * nH};
  mm_stream<3>(acc1, hib, nH, nH, Wp1, nH, m0, n0, tid, lane, mq, nq, As, Ws);
  ffrag acc2[3] = {};
  const unsigned short* const Wp2[3] = {Wih, Wih + (size_t)nH * nD, Wih + (size_t)2 * nH * nD};
  mm_stream<3>(acc2, ve + (size_t)t * nD, nT * nD, nD, Wp2, nD, m0, n0, tid, lane, mq, nq, As, Ws);

  const int col = n0 + nq * 16 + (lane & 15);
  const int rb = m0 + mq * 16 + ((lane >> 4) << 2);
  const float b_r = bih[col] + bhh[col];
  const float b_z = bih[nH + col] + bhh[nH + col];
  const float bi_n = bih[2 * nH + col];
  const float bh_n = bhh[2 * nH + col];
#pragma unroll
  for (int i = 0; i < 4; ++i) {
    const int row = rb + i;
    const size_t idx = (size_t)row * nH + col;
    const float rr = sigm(acc1[0][i] + acc2[0][i] + b_r);
    const float zv = sigm(acc1[1][i] + acc2[1][i] + b_z);
    const float nn = tanhf(acc2[2][i] + bi_n + rr * (acc1[2][i] + bh_n));
    const float hold = hif[idx];
    const float hnew = (1.f - zv) * nn + zv * hold;
    hof[idx] = hnew;
    const unsigned short h16 = f2b(hnew);
    hob[idx] = h16;
    hsb[((size_t)row * nT + t) * nH + col] = h16;
  }
}

// ---- attention pooling ----
__global__ void k_attn(const unsigned short* __restrict__ hsb,
                       const float* __restrict__ aw,
                       unsigned short* __restrict__ hencb) {
  __shared__ float sc[nT];
  __shared__ float al[nT];
  const int b = blockIdx.x;
  const int tid = threadIdx.x;
  const int w = tid >> 6, lane = tid & 63;
  for (int t = w; t < nT; t += 4) {
    const unsigned short* hr = hsb + ((size_t)b * nT + t) * nH;
    float s = 0.f;
    for (int i = lane; i < nH; i += 64) s += b2f(hr[i]) * aw[i];
#pragma unroll
    for (int o = 32; o > 0; o >>= 1) s += __shfl_xor(s, o);
    if (lane == 0) sc[t] = s;
  }
  __syncthreads();
  if (tid < nT) {
    float v = sc[tid];
    float mx = v;
#pragma unroll
    for (int o = 32; o > 0; o >>= 1) mx = fmaxf(mx, __shfl_xor(mx, o));
    float e = expf(v - mx);
    float su = e;
#pragma unroll
    for (int o = 32; o > 0; o >>= 1) su += __shfl_xor(su, o);
    al[tid] = e / su;
  }
  __syncthreads();
  for (int col = tid; col < nH; col += 256) {
    float a = 0.f;
    for (int t = 0; t < nT; ++t) a += al[t] * b2f(hsb[((size_t)b * nT + t) * nH + col]);
    hencb[(size_t)b * nH + col] = f2b(a);
  }
}

// ---- VAE head ----
__global__ __launch_bounds__(256) void k_vae(
    const unsigned short* __restrict__ hencb,
    const unsigned short* __restrict__ Wmu, const unsigned short* __restrict__ Wvar,
    const float* __restrict__ bmu, const float* __restrict__ bvar,
    const float* __restrict__ eps,
    float* __restrict__ hf, unsigned short* __restrict__ hb,
    const int* __restrict__ lidx, float* __restrict__ out) {
  __shared__ __align__(16) unsigned short As[2 * 2048];
  __shared__ __align__(16) unsigned short Ws[2 * 2 * 2048];
  const int tid = threadIdx.x, lane = tid & 63, w = tid >> 6;
  const int mq = w & 1, nq = w >> 1;
  const int m0 = blockIdx.x * 32, n0 = blockIdx.y * 32;
  ffrag acc[2] = {};
  const unsigned short* const Wp[2] = {Wmu, Wvar};
  mm_stream<2>(acc, hencb, nH, nH, Wp, nH, m0, n0, tid, lane, mq, nq, As, Ws);
  const int col = n0 + nq * 16 + (lane & 15);
  const int rb = m0 + mq * 16 + ((lane >> 4) << 2);
#pragma unroll
  for (int i = 0; i < 4; ++i) {
    const int row = rb + i;
    const size_t idx = (size_t)row * nH + col;
    const float mu = acc[0][i] + bmu[col];
    const float lv = acc[1][i] + bvar[col];
    const float z0 = mu + expf(0.5f * lv) * eps[idx];
    hf[idx] = z0;
    hb[idx] = f2b(z0);
    if (lidx[row] == 0) out[idx] = z0;  // pred_z[b, 0]
  }
}

// ---------------------------------------------------------------------------
// Persistent GRU-ODE RK4 integrator.
// Grid = 256 blocks (1/CU, co-resident). Block = rowband i (blockIdx&7; maps
// to XCD i under round-robin dispatch) x colblock j (blockIdx>>3).
// Whz/Whn column-slices live in LDS (2 x 64 KB) for all 800 matmul phases.
// RK4 state (h_base, h_stage, kacc, zz) lives in registers; only bf16 stage
// state xb (mm1 A-operand) and g (mm2 A-operand) round-trip via L2.
// Rowband barrier: 32 blocks, monotonic device-scope counter, release on
// arrive / acquire on depart (cross-XCD-safe per G16; XCD-local by swizzle).
// ---------------------------------------------------------------------------
DEVI void rb_bar(unsigned* c, unsigned tgt) {
  __syncthreads();                 // all waves' stores drained (vmcnt before barrier)
  if (threadIdx.x == 0) {
    __hip_atomic_fetch_add(c, 1u, __ATOMIC_RELEASE, __HIP_MEMORY_SCOPE_AGENT);
    while (__hip_atomic_load(c, __ATOMIC_ACQUIRE, __HIP_MEMORY_SCOPE_AGENT) < tgt)
      __builtin_amdgcn_s_sleep(2);
  }
  __syncthreads();                 // acquire (L1 inv) happened on this CU
}

// 32x32x1024 tile matmul: A-frags direct from global (row-major bf16, ld=1024),
// B-frags from swizzled LDS via two pre-XORed base pointers (immediate-folded).
// Even/odd k-step accumulator split breaks the dependent-MFMA chain.
DEVI ffrag mm1024(const unsigned short* ag, const unsigned short* w0,
                  const unsigned short* w1) {
  ffrag a0 = {0.f, 0.f, 0.f, 0.f}, a1 = {0.f, 0.f, 0.f, 0.f};
#pragma unroll
  for (int v = 0; v < 16; ++v) {
    bfrag af0 = *(const bfrag*)(ag + (2 * v) * 32);
    bfrag wf0 = *(const bfrag*)(w0 + v * 64);
    a0 = mfma16(af0, wf0, a0);
    bfrag af1 = *(const bfrag*)(ag + (2 * v + 1) * 32);
    bfrag wf1 = *(const bfrag*)(w1 + v * 64);
    a1 = mfma16(af1, wf1, a1);
  }
  return a0 + a1;
}

__global__ __launch_bounds__(256, 1) void k_ode_persist(
    const unsigned short* __restrict__ Wz_g, const unsigned short* __restrict__ Wn_g,
    const float* __restrict__ h0f, unsigned short* xb, unsigned short* gbuf,
    const float* __restrict__ ts, const int* __restrict__ lidx,
    float* __restrict__ out, unsigned* ctr) {
  __shared__ __align__(16) unsigned short Wz[32 * nH];   // 64 KB
  __shared__ __align__(16) unsigned short Wn[32 * nH];   // 64 KB
  const int tid = threadIdx.x, lane = tid & 63, w = tid >> 6;
  const int mq = w & 1, nq = w >> 1;
  const int i = blockIdx.x & 7, j = blockIdx.x >> 3;
  const int m0 = i * 32, n0 = j * 32;

  // stage weight column-slices into LDS (swizzled: blk ^ (row&7))
  {
    const int r = tid >> 3, b0 = tid & 7;
    const size_t gro = (size_t)(n0 + r) * nH;
#pragma unroll
    for (int t2 = 0; t2 < 16; ++t2) {
      const int blk = b0 + 8 * t2;
      const int off = (r * 128 + (blk ^ (r & 7))) * 8;
      *(uvec4*)(Wz + off) = *(const uvec4*)(Wz_g + gro + blk * 8);
      *(uvec4*)(Wn + off) = *(const uvec4*)(Wn_g + gro + blk * 8);
    }
  }

  const int col = n0 + nq * 16 + (lane & 15);            // owned output col
  const int row0 = m0 + mq * 16 + ((lane >> 4) << 2);    // owned output rows
  const int arow = m0 + mq * 16 + (lane & 15);           // A-frag row
  const int q = lane >> 4;
  const int rw = nq * 16 + (lane & 15);                  // W row read by this lane
  const int c3 = rw & 7, ch = c3 >> 2, cl = c3 & 3;
  // read addr(st) = rw*1024 + (st^ch)*32 + (q^cl)*8  -> two linear bases
  const unsigned short* wz0 = Wz + rw * 1024 + (q ^ cl) * 8 + ch * 32;
  const unsigned short* wz1 = Wz + rw * 1024 + (q ^ cl) * 8 + (1 ^ ch) * 32;
  const unsigned short* wn0 = Wn + rw * 1024 + (q ^ cl) * 8 + ch * 32;
  const unsigned short* wn1 = Wn + rw * 1024 + (q ^ cl) * 8 + (1 ^ ch) * 32;
  const unsigned short* axb = xb + (size_t)arow * nH + q * 8;
  const unsigned short* agb = gbuf + (size_t)arow * nH + q * 8;

  float hb[4], xv[4], ka[4];
  int lst[4];
#pragma unroll
  for (int ii = 0; ii < 4; ++ii) {
    hb[ii] = h0f[(size_t)(row0 + ii) * nH + col];
    xv[ii] = hb[ii];
    lst[ii] = lidx[row0 + ii];
  }
  unsigned* myc = ctr + i;
  unsigned ph = 0;
  __syncthreads();   // weights staged

  for (int s = 0; s < nNT - 1; ++s) {
    const float dt = ts[s + 1] - ts[s];
    for (int stg = 0; stg < 4; ++stg) {
      // ---- mm1: zz = sigmoid(x @ Whz^T); g = zz * x ----
      ffrag acc = mm1024(axb, wz0, wz1);
      float zv[4];
#pragma unroll
      for (int ii = 0; ii < 4; ++ii) {
        zv[ii] = sigm(acc[ii]);
        gbuf[(size_t)(row0 + ii) * nH + col] = f2b(zv[ii] * xv[ii]);
      }
      ph += 32; rb_bar(myc, ph);
      // ---- mm2: nn = tanh(g @ Whn^T); f = (1-zz)*(nn-x); stage update ----
      acc = mm1024(agb, wn0, wn1);
#pragma unroll
      for (int ii = 0; ii < 4; ++ii) {
        const float nn = tanhf(acc[ii]);
        const float fv = (1.f - zv[ii]) * (nn - xv[ii]);
        if (stg == 0)      { ka[ii] = fv;        xv[ii] = hb[ii] + 0.5f * dt * fv; }
        else if (stg == 1) { ka[ii] += 2.f * fv; xv[ii] = hb[ii] + 0.5f * dt * fv; }
        else if (stg == 2) { ka[ii] += 2.f * fv; xv[ii] = hb[ii] + dt * fv; }
        else {
          const float hn = hb[ii] + (dt * (1.f / 6.f)) * (ka[ii] + fv);
          hb[ii] = hn; xv[ii] = hn;
          if (lst[ii] == s + 1) out[(size_t)(row0 + ii) * nH + col] = hn;
        }
        xb[(size_t)(row0 + ii) * nH + col] = f2b(xv[ii]);
      }
      ph += 32; rb_bar(myc, ph);
    }
  }
}

}  // namespace

extern "C" void kernel_launch(void* const* d_in, const int* in_sizes, int n_in,
                              void* d_out, int out_size, void* d_ws, size_t ws_size,
                              hipStream_t stream) {
  const float* Hs   = (const float*)d_in[0];
  const float* ts   = (const float*)d_in[1];
  const int*   lidx = (const int*)d_in[2];
  const int*   llm  = (const int*)d_in[3];
  const float* eps  = (const float*)d_in[4];
  const float* emb  = (const float*)d_in[5];
  const float* Wih  = (const float*)d_in[6];
  const float* Whh  = (const float*)d_in[7];
  const float* bih  = (const float*)d_in[8];
  const float* bhh  = (const float*)d_in[9];
  const float* aw   = (const float*)d_in[10];
  const float* Wmu  = (const float*)d_in[11];
  const float* bmu  = (const float*)d_in[12];
  const float* Wvar = (const float*)d_in[13];
  const float* bvar = (const float*)d_in[14];
  const float* Whz  = (const float*)d_in[15];
  const float* Whn  = (const float*)d_in[16];

  float* out_last = (float*)d_out;
  float* out_mask = out_last + (size_t)nB * nH;

  char* p = (char*)d_ws;
  auto alloc = [&](size_t bytes) {
    void* r = p; p += (bytes + 255) & ~(size_t)255; return r;
  };
  unsigned short* Whh_b  = (unsigned short*)alloc((size_t)3 * nH * nH * 2);
  unsigned short* Wih_b  = (unsigned short*)alloc((size_t)3 * nH * nD * 2);
  unsigned short* Wmu_b  = (unsigned short*)alloc((size_t)nH * nH * 2);
  unsigned short* Wvar_b = (unsigned short*)alloc((size_t)nH * nH * 2);
  unsigned short* Whz_b  = (unsigned short*)alloc((size_t)nH * nH * 2);
  unsigned short* Whn_b  = (unsigned short*)alloc((size_t)nH * nH * 2);
  unsigned short* ve_b   = (unsigned short*)alloc((size_t)nB * nT * nD * 2);
  unsigned short* hs_b   = (unsigned short*)alloc((size_t)nB * nT * nH * 2);
  float* h0f             = (float*)alloc((size_t)nB * nH * 4);
  float* h1f             = (float*)alloc((size_t)nB * nH * 4);
  unsigned short* h0b    = (unsigned short*)alloc((size_t)nB * nH * 2);
  unsigned short* h1b    = (unsigned short*)alloc((size_t)nB * nH * 2);
  unsigned short* gb     = (unsigned short*)alloc((size_t)nB * nH * 2);
  unsigned short* hencb  = (unsigned short*)alloc((size_t)nB * nH * 2);
  unsigned* ctr          = (unsigned*)alloc(256);

  hipMemsetAsync(h0f, 0, (size_t)nB * nH * 4, stream);   // GRU h0 = 0
  hipMemsetAsync(h0b, 0, (size_t)nB * nH * 2, stream);
  hipMemsetAsync(ctr, 0, 256, stream);                   // rowband barrier counters

  auto cvt = [&](const float* s, unsigned short* d, int n) {
    k_cvt<<<n / 1024, 256, 0, stream>>>(s, d, n);
  };
  cvt(Whh, Whh_b, 3 * nH * nH);
  cvt(Wih, Wih_b, 3 * nH * nD);
  cvt(Wmu, Wmu_b, nH * nH);
  cvt(Wvar, Wvar_b, nH * nH);
  cvt(Whz, Whz_b, nH * nH);
  cvt(Whn, Whn_b, nH * nH);

  k_embed<<<nB, 256, 0, stream>>>(Hs, emb, ve_b);
  k_mask<<<dim3((nC + 255) / 256, nB), 256, 0, stream>>>(llm, out_mask);

  const dim3 gg(nB / 32, nH / 32);  // 8 x 32 = 256 blocks
  for (int t = 0; t < nT; ++t) {
    const unsigned short* hib = (t & 1) ? h1b : h0b;
    const float* hif = (t & 1) ? h1f : h0f;
    unsigned short* hob = (t & 1) ? h0b : h1b;
    float* hof = (t & 1) ? h0f : h1f;
    k_gru<<<gg, 256, 0, stream>>>(t, hib, hif, ve_b, Whh_b, Wih_b, bih, bhh,
                                  hof, hob, hs_b);
  }
  k_attn<<<nB, 256, 0, stream>>>(hs_b, aw, hencb);
  // z0 -> h0f (f32 state) + h0b (bf16, first mm1 A-operand)
  k_vae<<<gg, 256, 0, stream>>>(hencb, Wmu_b, Wvar_b, bmu, bvar, eps,
                                h0f, h0b, lidx, out_last);

  // entire 100-step RK4 GRU-ODE in one persistent kernel
  k_ode_persist<<<256, 256, 0, stream>>>(Whz_b, Whn_b, h0f, h0b, gb, ts, lidx,
                                         out_last, ctr);
}

// Round 3
// 7799.133 us; speedup vs baseline: 1.5482x; 1.5482x over previous
//
#include <hip/hip_runtime.h>
#include <hip/hip_bf16.h>

#define DEVI __device__ __forceinline__

namespace {

constexpr int nB = 256, nT = 64, nC = 4880, nD = 128, nH = 1024, nNT = 101, nND = 10;

typedef __attribute__((ext_vector_type(8))) short bfrag;   // 8 bf16 = 4 VGPR (MFMA A/B)
typedef __attribute__((ext_vector_type(4))) float ffrag;   // MFMA C/D
typedef __attribute__((ext_vector_type(4))) unsigned int uvec4;

DEVI ffrag mfma16(bfrag a, bfrag b, ffrag c) {
  return __builtin_amdgcn_mfma_f32_16x16x32_bf16(a, b, c, 0, 0, 0);
}

DEVI unsigned short f2b(float x) {
  __hip_bfloat16 h = __float2bfloat16(x);
  return *reinterpret_cast<unsigned short*>(&h);
}
DEVI float b2f(unsigned short u) {
  __hip_bfloat16 h;
  *reinterpret_cast<unsigned short*>(&h) = u;
  return __bfloat162float(h);
}
DEVI float sigm(float x) { return 1.f / (1.f + expf(-x)); }

// ---------------------------------------------------------------------------
// Double-buffered bf16 MFMA tile stream (GRU / VAE kernels — proven path).
// ---------------------------------------------------------------------------
template<int NS>
DEVI void mm_stream(ffrag (&acc)[NS],
                    const unsigned short* __restrict__ A, int lda, int K,
                    const unsigned short* const (&Wp)[NS], int ldw,
                    int m0, int n0, int tid, int lane, int mq, int nq,
                    unsigned short* As, unsigned short* Ws) {
  const int r = tid >> 3, blk = tid & 7;
  const int wrOff = (r * 8 + (blk ^ (r & 7))) * 8;   // ushort offset
  const int ra = mq * 16 + (lane & 15);              // A-frag row (m)
  const int rw = nq * 16 + (lane & 15);              // W-frag row (n)
  const int q = lane >> 4;                           // k-quadrant
  const int nc = K >> 6;                             // 64-wide K chunks

  uvec4 va = *(const uvec4*)(A + (size_t)(m0 + r) * lda + blk * 8);
  uvec4 vw[NS];
#pragma unroll
  for (int s = 0; s < NS; ++s)
    vw[s] = *(const uvec4*)(Wp[s] + (size_t)(n0 + r) * ldw + blk * 8);
  *(uvec4*)(As + wrOff) = va;
#pragma unroll
  for (int s = 0; s < NS; ++s) *(uvec4*)(Ws + s * 2048 + wrOff) = vw[s];

  for (int ci = 0; ci < nc; ++ci) {
    __syncthreads();
    const int cur = ci & 1;
    const bool more = (ci + 1) < nc;
    if (more) {
      const int k0 = (ci + 1) << 6;
      va = *(const uvec4*)(A + (size_t)(m0 + r) * lda + k0 + blk * 8);
#pragma unroll
      for (int s = 0; s < NS; ++s)
        vw[s] = *(const uvec4*)(Wp[s] + (size_t)(n0 + r) * ldw + k0 + blk * 8);
    }
    const unsigned short* Ab = As + cur * 2048;
    const unsigned short* Wb = Ws + cur * (NS * 2048);
#pragma unroll
    for (int kk = 0; kk < 2; ++kk) {
      bfrag af = *(const bfrag*)(Ab + (ra * 8 + ((kk * 4 + q) ^ (ra & 7))) * 8);
#pragma unroll
      for (int s = 0; s < NS; ++s) {
        bfrag wf = *(const bfrag*)(Wb + s * 2048 + (rw * 8 + ((kk * 4 + q) ^ (rw & 7))) * 8);
        acc[s] = mfma16(af, wf, acc[s]);
      }
    }
    if (more) {
      const int nx = cur ^ 1;
      *(uvec4*)(As + nx * 2048 + wrOff) = va;
#pragma unroll
      for (int s = 0; s < NS; ++s)
        *(uvec4*)(Ws + nx * (NS * 2048) + s * 2048 + wrOff) = vw[s];
    }
  }
  __syncthreads();
}

// ---- fp32 -> bf16 bulk convert (n divisible by 1024) ----
__global__ void k_cvt(const float* __restrict__ s, unsigned short* __restrict__ d, int n) {
  int i = blockIdx.x * blockDim.x + threadIdx.x;
  float4 v = ((const float4*)s)[i];
  unsigned int u0 = (unsigned int)f2b(v.x) | ((unsigned int)f2b(v.y) << 16);
  unsigned int u1 = (unsigned int)f2b(v.z) | ((unsigned int)f2b(v.w) << 16);
  ((uint2*)d)[i] = make_uint2(u0, u1);
}

// ---- LLM diagnosis mask ----
__global__ void k_mask(const int* __restrict__ llm, float* __restrict__ outm) {
  int c = blockIdx.x * 256 + threadIdx.x;
  int b = blockIdx.y;
  if (c >= nC) return;
  const int* lr = llm + b * nND;
  float v = 0.f;
#pragma unroll
  for (int i = 0; i < nND; ++i) v = (lr[i] == c) ? 1.f : v;
  outm[(size_t)b * nC + c] = v;
}

// ---- sparse visit embedding ----
__global__ void k_embed(const float* __restrict__ Hs, const float* __restrict__ emb,
                        unsigned short* __restrict__ ve) {
  __shared__ float tile[4][16][128];
  const int b = blockIdx.x;
  const int tid = threadIdx.x;
  const int w = tid >> 6, lane = tid & 63;
  float* tw = &tile[w][0][0];
  for (int i = lane; i < 16 * 128; i += 64) tw[i] = 0.f;
  const float* hb = Hs + (size_t)b * nC * nT;
  const int tq = w * 16;
  const int tl = lane & 15;
  const int co = lane >> 4;
  for (int cb = 0; cb < nC; cb += 4) {
    const int c = cb + co;
    float v = hb[(size_t)c * nT + tq + tl];
    unsigned long long m = __ballot(v != 0.f);
    while (m) {
      const int p = __ffsll(m) - 1;
      m &= m - 1;
      const int cc = cb + (p >> 4);
      const int tt = p & 15;
      const float vv = __shfl(v, p);
      const float* er = emb + (size_t)cc * nD;
      tile[w][tt][lane]      += vv * er[lane];
      tile[w][tt][lane + 64] += vv * er[lane + 64];
    }
  }
  for (int rr = 0; rr < 16; ++rr) {
    unsigned short* o = ve + ((size_t)b * nT + tq + rr) * nD;
    o[lane]      = f2b(tile[w][rr][lane]);
    o[lane + 64] = f2b(tile[w][rr][lane + 64]);
  }
}

// ---- one GRU step ----
__global__ __launch_bounds__(256) void k_gru(
    int t,
    const unsigned short* __restrict__ hib, const float* __restrict__ hif,
    const unsigned short* __restrict__ ve,
    const unsigned short* __restrict__ Whh, const unsigned short* __restrict__ Wih,
    const float* __restrict__ bih, const float* __restrict__ bhh,
    float* __restrict__ hof, unsigned short* __restrict__ hob,
    unsigned short* __restrict__ hsb) {
  __shared__ __align__(16) unsigned short As[2 * 2048];
  __shared__ __align__(16) unsigned short Ws[2 * 3 * 2048];
  const int tid = threadIdx.x, lane = tid & 63, w = tid >> 6;
  const int mq = w & 1, nq = w >> 1;
  const int m0 = blockIdx.x * 32, n0 = blockIdx.y * 32;

  ffrag acc1[3] = {};
  const unsigned short* const Wp1[3] = {Whh, Whh + (size_t)nH * nH, Whh + (size_t)2 * nH * nH};
  mm_stream<3>(acc1, hib, nH, nH, Wp1, nH, m0, n0, tid, lane, mq, nq, As, Ws);
  ffrag acc2[3] = {};
  const unsigned short* const Wp2[3] = {Wih, Wih + (size_t)nH * nD, Wih + (size_t)2 * nH * nD};
  mm_stream<3>(acc2, ve + (size_t)t * nD, nT * nD, nD, Wp2, nD, m0, n0, tid, lane, mq, nq, As, Ws);

  const int col = n0 + nq * 16 + (lane & 15);
  const int rb = m0 + mq * 16 + ((lane >> 4) << 2);
  const float b_r = bih[col] + bhh[col];
  const float b_z = bih[nH + col] + bhh[nH + col];
  const float bi_n = bih[2 * nH + col];
  const float bh_n = bhh[2 * nH + col];
#pragma unroll
  for (int i = 0; i < 4; ++i) {
    const int row = rb + i;
    const size_t idx = (size_t)row * nH + col;
    const float rr = sigm(acc1[0][i] + acc2[0][i] + b_r);
    const float zv = sigm(acc1[1][i] + acc2[1][i] + b_z);
    const float nn = tanhf(acc2[2][i] + bi_n + rr * (acc1[2][i] + bh_n));
    const float hold = hif[idx];
    const float hnew = (1.f - zv) * nn + zv * hold;
    hof[idx] = hnew;
    const unsigned short h16 = f2b(hnew);
    hob[idx] = h16;
    hsb[((size_t)row * nT + t) * nH + col] = h16;
  }
}

// ---- attention pooling ----
__global__ void k_attn(const unsigned short* __restrict__ hsb,
                       const float* __restrict__ aw,
                       unsigned short* __restrict__ hencb) {
  __shared__ float sc[nT];
  __shared__ float al[nT];
  const int b = blockIdx.x;
  const int tid = threadIdx.x;
  const int w = tid >> 6, lane = tid & 63;
  for (int t = w; t < nT; t += 4) {
    const unsigned short* hr = hsb + ((size_t)b * nT + t) * nH;
    float s = 0.f;
    for (int i = lane; i < nH; i += 64) s += b2f(hr[i]) * aw[i];
#pragma unroll
    for (int o = 32; o > 0; o >>= 1) s += __shfl_xor(s, o);
    if (lane == 0) sc[t] = s;
  }
  __syncthreads();
  if (tid < nT) {
    float v = sc[tid];
    float mx = v;
#pragma unroll
    for (int o = 32; o > 0; o >>= 1) mx = fmaxf(mx, __shfl_xor(mx, o));
    float e = expf(v - mx);
    float su = e;
#pragma unroll
    for (int o = 32; o > 0; o >>= 1) su += __shfl_xor(su, o);
    al[tid] = e / su;
  }
  __syncthreads();
  for (int col = tid; col < nH; col += 256) {
    float a = 0.f;
    for (int t = 0; t < nT; ++t) a += al[t] * b2f(hsb[((size_t)b * nT + t) * nH + col]);
    hencb[(size_t)b * nH + col] = f2b(a);
  }
}

// ---- VAE head ----
__global__ __launch_bounds__(256) void k_vae(
    const unsigned short* __restrict__ hencb,
    const unsigned short* __restrict__ Wmu, const unsigned short* __restrict__ Wvar,
    const float* __restrict__ bmu, const float* __restrict__ bvar,
    const float* __restrict__ eps,
    float* __restrict__ hf, unsigned short* __restrict__ hb,
    const int* __restrict__ lidx, float* __restrict__ out) {
  __shared__ __align__(16) unsigned short As[2 * 2048];
  __shared__ __align__(16) unsigned short Ws[2 * 2 * 2048];
  const int tid = threadIdx.x, lane = tid & 63, w = tid >> 6;
  const int mq = w & 1, nq = w >> 1;
  const int m0 = blockIdx.x * 32, n0 = blockIdx.y * 32;
  ffrag acc[2] = {};
  const unsigned short* const Wp[2] = {Wmu, Wvar};
  mm_stream<2>(acc, hencb, nH, nH, Wp, nH, m0, n0, tid, lane, mq, nq, As, Ws);
  const int col = n0 + nq * 16 + (lane & 15);
  const int rb = m0 + mq * 16 + ((lane >> 4) << 2);
#pragma unroll
  for (int i = 0; i < 4; ++i) {
    const int row = rb + i;
    const size_t idx = (size_t)row * nH + col;
    const float mu = acc[0][i] + bmu[col];
    const float lv = acc[1][i] + bvar[col];
    const float z0 = mu + expf(0.5f * lv) * eps[idx];
    hf[idx] = z0;
    hb[idx] = f2b(z0);
    if (lidx[row] == 0) out[idx] = z0;  // pred_z[b, 0]
  }
}

// ---------------------------------------------------------------------------
// ODE phase kernels — minimal-latency streaming matmul.
// 32x32 output tile, 4 waves (mq=w&1, nq=w>>1). W column-slice (32 x 1024)
// staged ONCE into LDS (64 KB) with 16B-unit XOR(row&7) swizzle (G4 recipe,
// conflict-free for both the linear stage-write and the frag ds_read_b128).
// A fragments are loaded directly from global (L2/L3-hot 512 KB buffer) —
// no A staging, exactly one __syncthreads per kernel. 32 MFMAs in two
// independent chains.
// ---------------------------------------------------------------------------
DEVI void stageW(const unsigned short* __restrict__ Wg, int n0, int tid,
                 unsigned short* Ws) {
  const int r = tid >> 3, b0 = tid & 7;
  const unsigned short* src = Wg + (size_t)(n0 + r) * nH;
  unsigned short* dst = Ws + r * 1024;
#pragma unroll
  for (int t2 = 0; t2 < 16; ++t2) {
    const int blk = b0 + 8 * t2;
    *(uvec4*)(dst + (blk ^ (r & 7)) * 8) = *(const uvec4*)(src + blk * 8);
  }
}

DEVI ffrag mmK1024(const unsigned short* __restrict__ ag,
                   const unsigned short* wrow, int q, int rx) {
  ffrag a0 = {0.f, 0.f, 0.f, 0.f}, a1 = {0.f, 0.f, 0.f, 0.f};
#pragma unroll
  for (int kk = 0; kk < 32; kk += 2) {
    bfrag af0 = *(const bfrag*)(ag + kk * 32);
    bfrag wf0 = *(const bfrag*)(wrow + (((kk * 4 + q) ^ rx) * 8));
    a0 = mfma16(af0, wf0, a0);
    bfrag af1 = *(const bfrag*)(ag + (kk + 1) * 32);
    bfrag wf1 = *(const bfrag*)(wrow + ((((kk + 1) * 4 + q) ^ rx) * 8));
    a1 = mfma16(af1, wf1, a1);
  }
  return a0 + a1;
}

// mm1: zz = sigmoid(x @ Whz^T); g = zz * x
__global__ __launch_bounds__(256) void k_mm1(
    const unsigned short* __restrict__ xb, const unsigned short* __restrict__ Wz,
    float* __restrict__ zzf, unsigned short* __restrict__ gbb) {
  __shared__ __align__(16) unsigned short Ws[32 * 1024];
  const int tid = threadIdx.x, lane = tid & 63, w = tid >> 6;
  const int mq = w & 1, nq = w >> 1;
  const int m0 = blockIdx.x * 32, n0 = blockIdx.y * 32;
  stageW(Wz, n0, tid, Ws);
  const int arow = m0 + mq * 16 + (lane & 15);
  const int q = lane >> 4;
  const int rw = nq * 16 + (lane & 15);
  const unsigned short* ag = xb + (size_t)arow * nH + q * 8;
  const unsigned short* wrow = Ws + rw * 1024;
  const int rx = rw & 7;
  __syncthreads();
  ffrag acc = mmK1024(ag, wrow, q, rx);
  const int col = n0 + nq * 16 + (lane & 15);
  const int rb = m0 + mq * 16 + ((lane >> 4) << 2);
#pragma unroll
  for (int i = 0; i < 4; ++i) {
    const size_t idx = (size_t)(rb + i) * nH + col;
    const float zv = sigm(acc[i]);
    zzf[idx] = zv;
    gbb[idx] = f2b(zv * b2f(xb[idx]));
  }
}

// mm2: nn = tanh(g @ Whn^T); f = (1-zz)*(nn - x); RK4 stage update
template<int STG>
__global__ __launch_bounds__(256) void k_mm2(
    const unsigned short* __restrict__ gbb, const unsigned short* __restrict__ Wn,
    const float* __restrict__ zzf, unsigned short* xb,
    float* hbf, float* __restrict__ kacc,
    const float* __restrict__ ts, int s,
    const int* __restrict__ lidx, float* __restrict__ out) {
  __shared__ __align__(16) unsigned short Ws[32 * 1024];
  const int tid = threadIdx.x, lane = tid & 63, w = tid >> 6;
  const int mq = w & 1, nq = w >> 1;
  const int m0 = blockIdx.x * 32, n0 = blockIdx.y * 32;
  stageW(Wn, n0, tid, Ws);
  const int arow = m0 + mq * 16 + (lane & 15);
  const int q = lane >> 4;
  const int rw = nq * 16 + (lane & 15);
  const unsigned short* ag = gbb + (size_t)arow * nH + q * 8;
  const unsigned short* wrow = Ws + rw * 1024;
  const int rx = rw & 7;
  __syncthreads();
  ffrag acc = mmK1024(ag, wrow, q, rx);
  const float dt = ts[s + 1] - ts[s];
  const int col = n0 + nq * 16 + (lane & 15);
  const int rb = m0 + mq * 16 + ((lane >> 4) << 2);
#pragma unroll
  for (int i = 0; i < 4; ++i) {
    const int row = rb + i;
    const size_t idx = (size_t)row * nH + col;
    const float nn = tanhf(acc[i]);
    const float zv = zzf[idx];
    const float fv = (1.f - zv) * (nn - b2f(xb[idx]));
    float xnew;
    if (STG == 0)      { kacc[idx] = fv;        xnew = hbf[idx] + 0.5f * dt * fv; }
    else if (STG == 1) { kacc[idx] += 2.f * fv; xnew = hbf[idx] + 0.5f * dt * fv; }
    else if (STG == 2) { kacc[idx] += 2.f * fv; xnew = hbf[idx] + dt * fv; }
    else {
      xnew = hbf[idx] + (dt * (1.f / 6.f)) * (kacc[idx] + fv);
      hbf[idx] = xnew;
      if (lidx[row] == s + 1) out[idx] = xnew;  // pred_z[b, s+1]
    }
    xb[idx] = f2b(xnew);
  }
}

}  // namespace

extern "C" void kernel_launch(void* const* d_in, const int* in_sizes, int n_in,
                              void* d_out, int out_size, void* d_ws, size_t ws_size,
                              hipStream_t stream) {
  const float* Hs   = (const float*)d_in[0];
  const float* ts   = (const float*)d_in[1];
  const int*   lidx = (const int*)d_in[2];
  const int*   llm  = (const int*)d_in[3];
  const float* eps  = (const float*)d_in[4];
  const float* emb  = (const float*)d_in[5];
  const float* Wih  = (const float*)d_in[6];
  const float* Whh  = (const float*)d_in[7];
  const float* bih  = (const float*)d_in[8];
  const float* bhh  = (const float*)d_in[9];
  const float* aw   = (const float*)d_in[10];
  const float* Wmu  = (const float*)d_in[11];
  const float* bmu  = (const float*)d_in[12];
  const float* Wvar = (const float*)d_in[13];
  const float* bvar = (const float*)d_in[14];
  const float* Whz  = (const float*)d_in[15];
  const float* Whn  = (const float*)d_in[16];

  float* out_last = (float*)d_out;
  float* out_mask = out_last + (size_t)nB * nH;

  char* p = (char*)d_ws;
  auto alloc = [&](size_t bytes) {
    void* r = p; p += (bytes + 255) & ~(size_t)255; return r;
  };
  unsigned short* Whh_b  = (unsigned short*)alloc((size_t)3 * nH * nH * 2);
  unsigned short* Wih_b  = (unsigned short*)alloc((size_t)3 * nH * nD * 2);
  unsigned short* Wmu_b  = (unsigned short*)alloc((size_t)nH * nH * 2);
  unsigned short* Wvar_b = (unsigned short*)alloc((size_t)nH * nH * 2);
  unsigned short* Whz_b  = (unsigned short*)alloc((size_t)nH * nH * 2);
  unsigned short* Whn_b  = (unsigned short*)alloc((size_t)nH * nH * 2);
  unsigned short* ve_b   = (unsigned short*)alloc((size_t)nB * nT * nD * 2);
  unsigned short* hs_b   = (unsigned short*)alloc((size_t)nB * nT * nH * 2);
  float* h0f             = (float*)alloc((size_t)nB * nH * 4);
  float* h1f             = (float*)alloc((size_t)nB * nH * 4);
  unsigned short* h0b    = (unsigned short*)alloc((size_t)nB * nH * 2);
  unsigned short* h1b    = (unsigned short*)alloc((size_t)nB * nH * 2);
  unsigned short* gb     = (unsigned short*)alloc((size_t)nB * nH * 2);
  unsigned short* hencb  = (unsigned short*)alloc((size_t)nB * nH * 2);
  float* zzf             = (float*)alloc((size_t)nB * nH * 4);
  float* kacc            = (float*)alloc((size_t)nB * nH * 4);

  hipMemsetAsync(h0f, 0, (size_t)nB * nH * 4, stream);   // GRU h0 = 0
  hipMemsetAsync(h0b, 0, (size_t)nB * nH * 2, stream);

  auto cvt = [&](const float* s, unsigned short* d, int n) {
    k_cvt<<<n / 1024, 256, 0, stream>>>(s, d, n);
  };
  cvt(Whh, Whh_b, 3 * nH * nH);
  cvt(Wih, Wih_b, 3 * nH * nD);
  cvt(Wmu, Wmu_b, nH * nH);
  cvt(Wvar, Wvar_b, nH * nH);
  cvt(Whz, Whz_b, nH * nH);
  cvt(Whn, Whn_b, nH * nH);

  k_embed<<<nB, 256, 0, stream>>>(Hs, emb, ve_b);
  k_mask<<<dim3((nC + 255) / 256, nB), 256, 0, stream>>>(llm, out_mask);

  const dim3 gg(nB / 32, nH / 32);  // 8 x 32 = 256 blocks
  for (int t = 0; t < nT; ++t) {
    const unsigned short* hib = (t & 1) ? h1b : h0b;
    const float* hif = (t & 1) ? h1f : h0f;
    unsigned short* hob = (t & 1) ? h0b : h1b;
    float* hof = (t & 1) ? h0f : h1f;
    k_gru<<<gg, 256, 0, stream>>>(t, hib, hif, ve_b, Whh_b, Wih_b, bih, bhh,
                                  hof, hob, hs_b);
  }
  k_attn<<<nB, 256, 0, stream>>>(hs_b, aw, hencb);
  // z0 -> h0f (f32 base state) + h0b (bf16, first mm1 A-operand)
  k_vae<<<gg, 256, 0, stream>>>(hencb, Wmu_b, Wvar_b, bmu, bvar, eps,
                                h0f, h0b, lidx, out_last);

  // RK4 GRU-ODE: 100 steps x 4 stages x 2 matmul phases (launch = barrier)
  for (int s = 0; s < nNT - 1; ++s) {
    k_mm1<<<gg, 256, 0, stream>>>(h0b, Whz_b, zzf, gb);
    k_mm2<0><<<gg, 256, 0, stream>>>(gb, Whn_b, zzf, h0b, h0f, kacc, ts, s, lidx, out_last);
    k_mm1<<<gg, 256, 0, stream>>>(h0b, Whz_b, zzf, gb);
    k_mm2<1><<<gg, 256, 0, stream>>>(gb, Whn_b, zzf, h0b, h0f, kacc, ts, s, lidx, out_last);
    k_mm1<<<gg, 256, 0, stream>>>(h0b, Whz_b, zzf, gb);
    k_mm2<2><<<gg, 256, 0, stream>>>(gb, Whn_b, zzf, h0b, h0f, kacc, ts, s, lidx, out_last);
    k_mm1<<<gg, 256, 0, stream>>>(h0b, Whz_b, zzf, gb);
    k_mm2<3><<<gg, 256, 0, stream>>>(gb, Whn_b, zzf, h0b, h0f, kacc, ts, s, lidx, out_last);
  }
}